// Round 12
// baseline (662.834 us; speedup 1.0000x reference)
//
#include <hip/hip_runtime.h>
#include <hip/hip_bf16.h>
#include <cstdint>
#include <cstddef>

typedef __bf16 bf16;
typedef __bf16 bf16x8 __attribute__((ext_vector_type(8)));
typedef float f32x4 __attribute__((ext_vector_type(4)));

#define N_PTS 131072
#define CDIM  512
#define C3    1536
#define HD    64
#define NH    8
#define KWIN  128

static __device__ __forceinline__ bf16 cvt(float x) { return (bf16)x; }

// async global->LDS, 16B per lane. LDS dest = wave-uniform base + lane*16.
static __device__ __forceinline__ void gld16(const bf16* g, bf16* l) {
    __builtin_amdgcn_global_load_lds(
        (const __attribute__((address_space(1))) void*)g,
        (__attribute__((address_space(3))) void*)l, 16, 0, 0);
}

// ---------------------------------------------------------------------------
// Weight prep: transpose + cast f32 -> bf16.  Wt[col][k] = W[k][col].
// ---------------------------------------------------------------------------
__global__ __launch_bounds__(256) void k_prep(
    const float* __restrict__ Wqkv, const float* __restrict__ Wproj,
    bf16* __restrict__ Wqkv_t, bf16* __restrict__ Wproj_t)
{
    int idx = blockIdx.x * 256 + threadIdx.x;
    if (idx < CDIM * C3) {
        int k = idx / C3, c = idx % C3;
        Wqkv_t[(size_t)c * CDIM + k] = cvt(Wqkv[idx]);
    } else {
        int j = idx - CDIM * C3;
        if (j < CDIM * CDIM) {
            int k = j / CDIM, c = j % CDIM;
            Wproj_t[(size_t)c * CDIM + k] = cvt(Wproj[j]);
        }
    }
}

// ---------------------------------------------------------------------------
// Gather + cast: feat_g[i][:] = bf16(feat[order[i]][:])
// ---------------------------------------------------------------------------
__global__ __launch_bounds__(256) void k_gather(
    const float* __restrict__ feat, const int* __restrict__ order,
    bf16* __restrict__ feat_g)
{
    int row = blockIdx.x * 2 + (threadIdx.x >> 7);
    int c   = (threadIdx.x & 127) << 2;
    int src = order[row];
    float4 v = *reinterpret_cast<const float4*>(feat + (size_t)src * CDIM + c);
    union { bf16 e[4]; uint2 u; } pk;
    pk.e[0] = cvt(v.x); pk.e[1] = cvt(v.y); pk.e[2] = cvt(v.z); pk.e[3] = cvt(v.w);
    *reinterpret_cast<uint2*>(feat_g + (size_t)row * CDIM + c) = pk.u;
}

// ---------------------------------------------------------------------------
// 8-phase GEMM for qkv (R11, unchanged): out = A @ Bt^T + bias, bf16 out.
// ---------------------------------------------------------------------------
template <int NT>
__global__ __launch_bounds__(512) void k_gemm8(
    const bf16* __restrict__ Ag, const bf16* __restrict__ Bt,
    const float* __restrict__ bias, bf16* __restrict__ outp)
{
    __shared__ __align__(16) bf16 As[2][256 * 64];
    __shared__ __align__(16) bf16 Bs[2][256 * 64];

    const int t    = threadIdx.x;
    const int lane = t & 63;
    const int wv   = t >> 6;
    const int wr   = wv >> 2;
    const int wc   = wv & 3;
    const int g    = lane >> 4, r16 = lane & 15;

    const int nwg = gridDim.x;
    const int bid = blockIdx.x;
    const int swz = (bid & 7) * (nwg >> 3) + (bid >> 3);
    const int m0  = (swz / NT) * 256;
    const int n0  = (swz % NT) * 256;

    const int NKT = CDIM / 64;

    int aSrc[2][2], bSrc[2][2], dstE[2][2];
#pragma unroll
    for (int h = 0; h < 2; ++h)
#pragma unroll
        for (int j = 0; j < 2; ++j) {
            int L = wv * 128 + j * 64 + lane;
            int row_l = L >> 3, p8 = L & 7;
            int s8 = (p8 - (row_l & 7)) & 7;
            int grow = h * 128 + row_l;
            aSrc[h][j] = (m0 + grow) * CDIM + s8 * 8;
            bSrc[h][j] = (n0 + grow) * CDIM + s8 * 8;
            dstE[h][j] = h * 8192 + (wv * 128 + j * 64) * 8;
        }

    int aoff[2][2][4];
    int boff[2][4];
#pragma unroll
    for (int grp = 0; grp < 2; ++grp)
#pragma unroll
        for (int kh = 0; kh < 2; ++kh)
#pragma unroll
            for (int q = 0; q < 4; ++q) {
                int row = wr * 128 + (grp * 4 + q) * 16 + r16;
                aoff[grp][kh][q] = row * 128 +
                    (((kh * 4 + g + (r16 & 7)) & 7) << 4);
            }
#pragma unroll
    for (int kh = 0; kh < 2; ++kh)
#pragma unroll
        for (int n = 0; n < 4; ++n) {
            int row = wc * 64 + n * 16 + r16;
            boff[kh][n] = row * 128 +
                (((kh * 4 + g + (r16 & 7)) & 7) << 4);
        }

    f32x4 acc[8][4];
    const f32x4 z = {0.f, 0.f, 0.f, 0.f};
#pragma unroll
    for (int i = 0; i < 8; ++i)
#pragma unroll
        for (int n = 0; n < 4; ++n) acc[i][n] = z;

    bf16x8 afr[2][4], bfr[2][4];

    auto stageA = [&](int tau) {
        const int b = tau & 1, ko = tau * 64;
#pragma unroll
        for (int h = 0; h < 2; ++h)
#pragma unroll
            for (int j = 0; j < 2; ++j)
                gld16(Ag + aSrc[h][j] + ko, &As[b][dstE[h][j]]);
    };
    auto stageB = [&](int tau) {
        const int b = tau & 1, ko = tau * 64;
#pragma unroll
        for (int h = 0; h < 2; ++h)
#pragma unroll
            for (int j = 0; j < 2; ++j)
                gld16(Bt + bSrc[h][j] + ko, &Bs[b][dstE[h][j]]);
    };
    auto readA = [&](int set, int b, int grp, int kh) {
        const char* ab = reinterpret_cast<const char*>(&As[b][0]);
#pragma unroll
        for (int q = 0; q < 4; ++q)
            afr[set][q] = *reinterpret_cast<const bf16x8*>(ab + aoff[grp][kh][q]);
    };
    auto readB = [&](int b, int kh) {
        const char* bb = reinterpret_cast<const char*>(&Bs[b][0]);
#pragma unroll
        for (int n = 0; n < 4; ++n)
            bfr[kh][n] = *reinterpret_cast<const bf16x8*>(bb + boff[kh][n]);
    };

    stageB(0); stageA(0); stageB(1); stageA(1);
    asm volatile("s_waitcnt vmcnt(8)" ::: "memory");
    __builtin_amdgcn_s_barrier();
    readA(0, 0, 0, 0);
    readB(0, 0);
    asm volatile("s_waitcnt lgkmcnt(0)" ::: "memory");
    __builtin_amdgcn_sched_barrier(0);

#pragma unroll
    for (int tau = 0; tau < NKT; ++tau) {
#pragma unroll
        for (int p = 0; p < 4; ++p) {
            const int pi  = tau * 4 + p;
            const int grp = p & 1, kh = p >> 1;

            if (p == 2 && tau + 2 < NKT) stageB(tau + 2);
            if (p == 3 && tau + 2 < NKT) stageA(tau + 2);

            if (pi + 1 < NKT * 4) {
                const int pn   = (p + 1) & 3;
                const int taun = tau + (p == 3);
                const int bn   = taun & 1;
                readA((pi + 1) & 1, bn, pn & 1, pn >> 1);
                if (pn == 0 || pn == 2) readB(bn, pn >> 1);
            }

            __builtin_amdgcn_s_setprio(1);
#pragma unroll
            for (int q = 0; q < 4; ++q)
#pragma unroll
                for (int n = 0; n < 4; ++n)
                    acc[grp * 4 + q][n] = __builtin_amdgcn_mfma_f32_16x16x32_bf16(
                        afr[pi & 1][q], bfr[kh][n], acc[grp * 4 + q][n], 0, 0, 0);
            __builtin_amdgcn_s_setprio(0);

            asm volatile("s_waitcnt lgkmcnt(0)" ::: "memory");
            __builtin_amdgcn_sched_barrier(0);
            if (p == 2) {
                if (tau + 2 < NKT)
                    asm volatile("s_waitcnt vmcnt(4)" ::: "memory");
                else
                    asm volatile("s_waitcnt vmcnt(0)" ::: "memory");
            }
            __builtin_amdgcn_s_barrier();
        }
    }

    const int ldo = NT * 256;
#pragma unroll
    for (int n = 0; n < 4; ++n) {
        int col = n0 + wc * 64 + n * 16 + r16;
        float b = bias[col];
#pragma unroll
        for (int i = 0; i < 8; ++i)
#pragma unroll
            for (int j = 0; j < 4; ++j) {
                int row = m0 + wr * 128 + i * 16 + g * 4 + j;
                outp[(size_t)row * ldo + col] = cvt(acc[i][n][j] + b);
            }
    }
}

// ---------------------------------------------------------------------------
// FUSED attention + projection. One block per window (512 thr, 8 waves).
// Per head h: stage Q,K,V (48KB) + Wp k-slice (64KB, R5 rotate-permute) ->
// QK^T (wave = 16 Q-rows) -> softmax -> PV -> O_h to LDS ->
// proj partial: pacc[c][q] += Wp_t[c][d] * O_h[q][d]  (operand-swapped GEMM:
// A = Wp_t fragment [row=c][k=d], B = O_h [col=q][k=d] -> D = out^T).
// Epilogue: out[ord_s[q]][c..c+3] float4 stores (+bproj).
// LDS: Q/Kt 36.9K (P overlaps) + Vt 17.4K + Oh 18.4K + Wp 64K + ord = 138.7KB.
// ---------------------------------------------------------------------------
__global__ __launch_bounds__(512) void k_attn_proj(
    const bf16* __restrict__ qkv_s, const bf16* __restrict__ Wp_t,
    const float* __restrict__ bproj, const int* __restrict__ order,
    float* __restrict__ out)
{
    __shared__ __align__(16) char smem[138240];
    __shared__ int ord_s[KWIN];
    bf16 (*Q)[72]   = reinterpret_cast<bf16 (*)[72]>(smem);
    bf16 (*Kt)[72]  = reinterpret_cast<bf16 (*)[72]>(smem + 18432);
    bf16 (*P)[136]  = reinterpret_cast<bf16 (*)[136]>(smem);          // overlaps Q,Kt
    bf16 (*Vt)[136] = reinterpret_cast<bf16 (*)[136]>(smem + 36864);
    bf16 (*Oh)[72]  = reinterpret_cast<bf16 (*)[72]>(smem + 54272);
    bf16* Wp        = reinterpret_cast<bf16*>(smem + 72704);          // [2][512*32]

    const int t    = threadIdx.x;
    const int lane = t & 63;
    const int wv   = t >> 6;          // 0..7
    const int g    = lane >> 4, r16 = lane & 15;
    const int w    = blockIdx.x;

    if (t < KWIN) ord_s[t] = order[w * KWIN + t];

    // Wp staging map (R5 pattern): chunk L = q4*512 + t; row=L>>2, slot p=L&3,
    // src k-slot s=(p-(row>>1))&3. 4 chunks/thread per 32-k buffer.
    int wpRow[4], wpSlot[4];
#pragma unroll
    for (int q4 = 0; q4 < 4; ++q4) {
        int L = q4 * 512 + t;
        wpRow[q4]  = L >> 2;
        wpSlot[q4] = ((L & 3) - (wpRow[q4] >> 1)) & 3;
    }

    // proj A-frag offsets (rows = out-cols c), rotate-permute slots
    int paoff[4];
#pragma unroll
    for (int ci = 0; ci < 4; ++ci) {
        int row = wv * 64 + ci * 16 + r16;
        paoff[ci] = row * 64 + (((g + (row >> 1)) & 3) << 4);
    }

    f32x4 pacc[4][8];
    const f32x4 z = {0.f, 0.f, 0.f, 0.f};
#pragma unroll
    for (int ci = 0; ci < 4; ++ci)
#pragma unroll
        for (int qi = 0; qi < 8; ++qi) pacc[ci][qi] = z;

    const float scale = 0.125f;   // hd^-0.5

    for (int h = 0; h < NH; ++h) {
        // ---- stage Q,K,V of head h ----
        const bf16* base = qkv_s + (size_t)w * KWIN * C3 + h * HD;
#pragma unroll
        for (int it = 0; it < 2; ++it) {
            int s   = it * 512 + t;      // 0..1023
            int tok = s >> 3;
            int c8  = (s & 7) << 3;
            size_t roff = (size_t)tok * C3 + c8;
            *reinterpret_cast<uint4*>(&Q[tok][c8])  =
                *reinterpret_cast<const uint4*>(base + roff);
            *reinterpret_cast<uint4*>(&Kt[tok][c8]) =
                *reinterpret_cast<const uint4*>(base + roff + CDIM);
            uint4 vvec = *reinterpret_cast<const uint4*>(base + roff + 2 * CDIM);
            const bf16* ve = reinterpret_cast<const bf16*>(&vvec);
#pragma unroll
            for (int i = 0; i < 8; ++i) Vt[c8 + i][tok] = ve[i];
        }
        // ---- stage Wp k-slice of head h (both 32-k buffers) ----
#pragma unroll
        for (int ks = 0; ks < 2; ++ks)
#pragma unroll
            for (int q4 = 0; q4 < 4; ++q4) {
                gld16(Wp_t + (size_t)wpRow[q4] * CDIM + h * HD + ks * 32
                          + wpSlot[q4] * 8,
                      Wp + ks * 16384 + (q4 * 512 + wv * 64) * 8);
            }
        __syncthreads();

        // ---- QK^T: wave owns 16 Q-rows (wv*16 ..) ----
        f32x4 sc[8];
#pragma unroll
        for (int n = 0; n < 8; ++n) sc[n] = z;
#pragma unroll
        for (int ks = 0; ks < 2; ++ks) {
            bf16x8 aq = *reinterpret_cast<const bf16x8*>(
                &Q[wv * 16 + r16][ks * 32 + g * 8]);
#pragma unroll
            for (int n = 0; n < 8; ++n) {
                bf16x8 bk = *reinterpret_cast<const bf16x8*>(
                    &Kt[n * 16 + r16][ks * 32 + g * 8]);
                sc[n] = __builtin_amdgcn_mfma_f32_16x16x32_bf16(
                    aq, bk, sc[n], 0, 0, 0);
            }
        }

        // ---- softmax (rows wv*16 + g*4 + j), 16-lane-group reduce ----
        float inv_sum[4];
#pragma unroll
        for (int j = 0; j < 4; ++j) {
            float mx = -3.0e38f;
#pragma unroll
            for (int n = 0; n < 8; ++n) mx = fmaxf(mx, sc[n][j]);
            mx = fmaxf(mx, __shfl_xor(mx, 1));
            mx = fmaxf(mx, __shfl_xor(mx, 2));
            mx = fmaxf(mx, __shfl_xor(mx, 4));
            mx = fmaxf(mx, __shfl_xor(mx, 8));
            mx *= scale;
            float ssum = 0.f;
#pragma unroll
            for (int n = 0; n < 8; ++n) {
                float p = __expf(sc[n][j] * scale - mx);
                sc[n][j] = p;
                ssum += p;
            }
            ssum += __shfl_xor(ssum, 1);
            ssum += __shfl_xor(ssum, 2);
            ssum += __shfl_xor(ssum, 4);
            ssum += __shfl_xor(ssum, 8);
            inv_sum[j] = 1.f / ssum;
        }

        __syncthreads();   // all waves done reading Q/Kt before P overwrites

        // ---- write normalized P (bf16), own rows ----
#pragma unroll
        for (int n = 0; n < 8; ++n)
#pragma unroll
            for (int j = 0; j < 4; ++j)
                P[wv * 16 + g * 4 + j][n * 16 + r16] =
                    cvt(sc[n][j] * inv_sum[j]);

        // ---- O = P V  (16x64 per wave) ----
        f32x4 o[4];
#pragma unroll
        for (int n = 0; n < 4; ++n) o[n] = z;
#pragma unroll
        for (int kt = 0; kt < 4; ++kt) {
            bf16x8 ap = *reinterpret_cast<const bf16x8*>(
                &P[wv * 16 + r16][kt * 32 + g * 8]);
#pragma unroll
            for (int n = 0; n < 4; ++n) {
                bf16x8 bvv = *reinterpret_cast<const bf16x8*>(
                    &Vt[n * 16 + r16][kt * 32 + g * 8]);
                o[n] = __builtin_amdgcn_mfma_f32_16x16x32_bf16(
                    ap, bvv, o[n], 0, 0, 0);
            }
        }

        // ---- O_h to LDS (row-major [tok][d]) ----
#pragma unroll
        for (int n = 0; n < 4; ++n)
#pragma unroll
            for (int j = 0; j < 4; ++j)
                Oh[wv * 16 + g * 4 + j][n * 16 + r16] = cvt(o[n][j]);

        __syncthreads();   // Oh complete + Wp resident (syncthreads drains vm)

        // ---- proj partial: pacc[c][q] += Wp[c][d] * Oh[q][d], d = 64 ----
#pragma unroll
        for (int ks = 0; ks < 2; ++ks) {
            const char* wb = reinterpret_cast<const char*>(Wp + ks * 16384);
            bf16x8 af[4], bq[8];
#pragma unroll
            for (int ci = 0; ci < 4; ++ci)
                af[ci] = *reinterpret_cast<const bf16x8*>(wb + paoff[ci]);
#pragma unroll
            for (int qi = 0; qi < 8; ++qi)
                bq[qi] = *reinterpret_cast<const bf16x8*>(
                    &Oh[qi * 16 + r16][ks * 32 + g * 8]);
            __builtin_amdgcn_s_setprio(1);
#pragma unroll
            for (int ci = 0; ci < 4; ++ci)
#pragma unroll
                for (int qi = 0; qi < 8; ++qi)
                    pacc[ci][qi] = __builtin_amdgcn_mfma_f32_16x16x32_bf16(
                        af[ci], bq[qi], pacc[ci][qi], 0, 0, 0);
            __builtin_amdgcn_s_setprio(0);
        }
        __syncthreads();   // before next head's staging overwrites LDS
    }

    // ---- epilogue: D[c][q] = out^T; store float4 per (ci,qi) frag ----
    // D layout: q = qi*16 + (lane&15); c = wv*64 + ci*16 + (lane>>4)*4 + j.
#pragma unroll
    for (int ci = 0; ci < 4; ++ci) {
        int c0 = wv * 64 + ci * 16 + g * 4;
        float4 bp = *reinterpret_cast<const float4*>(bproj + c0);
#pragma unroll
        for (int qi = 0; qi < 8; ++qi) {
            int q = qi * 16 + r16;
            float4 v;
            v.x = pacc[ci][qi][0] + bp.x;
            v.y = pacc[ci][qi][1] + bp.y;
            v.z = pacc[ci][qi][2] + bp.z;
            v.w = pacc[ci][qi][3] + bp.w;
            *reinterpret_cast<float4*>(
                out + (size_t)ord_s[q] * CDIM + c0) = v;
        }
    }
}

// ---------------------------------------------------------------------------
extern "C" void kernel_launch(void* const* d_in, const int* in_sizes, int n_in,
                              void* d_out, int out_size, void* d_ws, size_t ws_size,
                              hipStream_t stream)
{
    const float* feat    = (const float*)d_in[0];
    const float* Wqkv    = (const float*)d_in[1];
    const float* bqkv    = (const float*)d_in[2];
    const float* Wproj   = (const float*)d_in[3];
    const float* bproj   = (const float*)d_in[4];
    const int*   order   = (const int*)d_in[5];
    float* out = (float*)d_out;

    const size_t qkv_bytes = (size_t)N_PTS * C3 * sizeof(bf16);    // 402.7 MB
    const size_t gat_bytes = (size_t)N_PTS * CDIM * sizeof(bf16);  // 134.2 MB
    const size_t wq_bytes  = (size_t)C3 * CDIM * sizeof(bf16);
    const size_t wp_bytes  = (size_t)CDIM * CDIM * sizeof(bf16);
    if (ws_size < qkv_bytes + gat_bytes + wq_bytes + wp_bytes) return;

    bf16* qkv_s   = (bf16*)d_ws;
    bf16* feat_g  = (bf16*)((char*)d_ws + qkv_bytes);
    bf16* Wqkv_t  = (bf16*)((char*)d_ws + qkv_bytes + gat_bytes);
    bf16* Wproj_t = (bf16*)((char*)d_ws + qkv_bytes + gat_bytes + wq_bytes);

    k_prep<<<dim3((CDIM * C3 + CDIM * CDIM + 255) / 256), 256, 0, stream>>>(
        Wqkv, Wproj, Wqkv_t, Wproj_t);
    k_gather<<<dim3(N_PTS / 2), 256, 0, stream>>>(feat, order, feat_g);
    // qkv GEMM: [131072 x 1536] = feat_g @ Wqkv_t^T  (512 x 6 = 3072 blocks)
    k_gemm8<C3 / 256><<<dim3((N_PTS / 256) * (C3 / 256)), 512, 0, stream>>>(
        feat_g, Wqkv_t, bqkv, qkv_s);
    // fused attention + projection: one block per window
    k_attn_proj<<<dim3(N_PTS / KWIN), 512, 0, stream>>>(
        qkv_s, Wproj_t, bproj, order, out);
}

// Round 13
// 653.924 us; speedup vs baseline: 1.0136x; 1.0136x over previous
//
#include <hip/hip_runtime.h>
#include <hip/hip_bf16.h>
#include <cstdint>
#include <cstddef>

typedef __bf16 bf16;
typedef __bf16 bf16x8 __attribute__((ext_vector_type(8)));
typedef float f32x4 __attribute__((ext_vector_type(4)));

#define N_PTS 131072
#define CDIM  512
#define C3    1536
#define HD    64
#define NH    8
#define KWIN  128

static __device__ __forceinline__ bf16 cvt(float x) { return (bf16)x; }

// async global->LDS, 16B per lane. LDS dest = wave-uniform base + lane*16.
static __device__ __forceinline__ void gld16(const bf16* g, bf16* l) {
    __builtin_amdgcn_global_load_lds(
        (const __attribute__((address_space(1))) void*)g,
        (__attribute__((address_space(3))) void*)l, 16, 0, 0);
}

// rotate a 128-bit value right by r 16-bit elements (r uniform per lane,
// 0..7): out elem k = in elem (k+r)&7. Branchless selects -> all static.
static __device__ __forceinline__ uint4 rot128(uint4 u, int r) {
    uint32_t x = u.x, y = u.y, z = u.z, w = u.w;
    uint32_t x1 = (x >> 16) | (y << 16), y1 = (y >> 16) | (z << 16),
             z1 = (z >> 16) | (w << 16), w1 = (w >> 16) | (x << 16);
    bool o1 = r & 1;
    x = o1 ? x1 : x; y = o1 ? y1 : y; z = o1 ? z1 : z; w = o1 ? w1 : w;
    bool o2 = r & 2;
    uint32_t t0 = x;
    x = o2 ? y : x; y = o2 ? z : y; z = o2 ? w : z; w = o2 ? t0 : w;
    bool o4 = r & 4;
    uint32_t tx = x, ty = y;
    x = o4 ? z : x; y = o4 ? w : y; z = o4 ? tx : z; w = o4 ? ty : w;
    uint4 o; o.x = x; o.y = y; o.z = z; o.w = w; return o;
}

// ---------------------------------------------------------------------------
// Weight prep: transpose + cast f32 -> bf16.  Wt[col][k] = W[k][col].
// ---------------------------------------------------------------------------
__global__ __launch_bounds__(256) void k_prep(
    const float* __restrict__ Wqkv, const float* __restrict__ Wproj,
    bf16* __restrict__ Wqkv_t, bf16* __restrict__ Wproj_t)
{
    int idx = blockIdx.x * 256 + threadIdx.x;
    if (idx < CDIM * C3) {
        int k = idx / C3, c = idx % C3;
        Wqkv_t[(size_t)c * CDIM + k] = cvt(Wqkv[idx]);
    } else {
        int j = idx - CDIM * C3;
        if (j < CDIM * CDIM) {
            int k = j / CDIM, c = j % CDIM;
            Wproj_t[(size_t)c * CDIM + k] = cvt(Wproj[j]);
        }
    }
}

// ---------------------------------------------------------------------------
// Gather + cast: feat_g[i][:] = bf16(feat[order[i]][:])
// ---------------------------------------------------------------------------
__global__ __launch_bounds__(256) void k_gather(
    const float* __restrict__ feat, const int* __restrict__ order,
    bf16* __restrict__ feat_g)
{
    int row = blockIdx.x * 2 + (threadIdx.x >> 7);
    int c   = (threadIdx.x & 127) << 2;
    int src = order[row];
    float4 v = *reinterpret_cast<const float4*>(feat + (size_t)src * CDIM + c);
    union { bf16 e[4]; uint2 u; } pk;
    pk.e[0] = cvt(v.x); pk.e[1] = cvt(v.y); pk.e[2] = cvt(v.z); pk.e[3] = cvt(v.w);
    *reinterpret_cast<uint2*>(feat_g + (size_t)row * CDIM + c) = pk.u;
}

// ---------------------------------------------------------------------------
// 8-phase GEMM for qkv (R11, unchanged): out = A @ Bt^T + bias, bf16 out.
// ---------------------------------------------------------------------------
template <int NT>
__global__ __launch_bounds__(512) void k_gemm8(
    const bf16* __restrict__ Ag, const bf16* __restrict__ Bt,
    const float* __restrict__ bias, bf16* __restrict__ outp)
{
    __shared__ __align__(16) bf16 As[2][256 * 64];
    __shared__ __align__(16) bf16 Bs[2][256 * 64];

    const int t    = threadIdx.x;
    const int lane = t & 63;
    const int wv   = t >> 6;
    const int wr   = wv >> 2;
    const int wc   = wv & 3;
    const int g    = lane >> 4, r16 = lane & 15;

    const int nwg = gridDim.x;
    const int bid = blockIdx.x;
    const int swz = (bid & 7) * (nwg >> 3) + (bid >> 3);
    const int m0  = (swz / NT) * 256;
    const int n0  = (swz % NT) * 256;

    const int NKT = CDIM / 64;

    int aSrc[2][2], bSrc[2][2], dstE[2][2];
#pragma unroll
    for (int h = 0; h < 2; ++h)
#pragma unroll
        for (int j = 0; j < 2; ++j) {
            int L = wv * 128 + j * 64 + lane;
            int row_l = L >> 3, p8 = L & 7;
            int s8 = (p8 - (row_l & 7)) & 7;
            int grow = h * 128 + row_l;
            aSrc[h][j] = (m0 + grow) * CDIM + s8 * 8;
            bSrc[h][j] = (n0 + grow) * CDIM + s8 * 8;
            dstE[h][j] = h * 8192 + (wv * 128 + j * 64) * 8;
        }

    int aoff[2][2][4];
    int boff[2][4];
#pragma unroll
    for (int grp = 0; grp < 2; ++grp)
#pragma unroll
        for (int kh = 0; kh < 2; ++kh)
#pragma unroll
            for (int q = 0; q < 4; ++q) {
                int row = wr * 128 + (grp * 4 + q) * 16 + r16;
                aoff[grp][kh][q] = row * 128 +
                    (((kh * 4 + g + (r16 & 7)) & 7) << 4);
            }
#pragma unroll
    for (int kh = 0; kh < 2; ++kh)
#pragma unroll
        for (int n = 0; n < 4; ++n) {
            int row = wc * 64 + n * 16 + r16;
            boff[kh][n] = row * 128 +
                (((kh * 4 + g + (r16 & 7)) & 7) << 4);
        }

    f32x4 acc[8][4];
    const f32x4 z = {0.f, 0.f, 0.f, 0.f};
#pragma unroll
    for (int i = 0; i < 8; ++i)
#pragma unroll
        for (int n = 0; n < 4; ++n) acc[i][n] = z;

    bf16x8 afr[2][4], bfr[2][4];

    auto stageA = [&](int tau) {
        const int b = tau & 1, ko = tau * 64;
#pragma unroll
        for (int h = 0; h < 2; ++h)
#pragma unroll
            for (int j = 0; j < 2; ++j)
                gld16(Ag + aSrc[h][j] + ko, &As[b][dstE[h][j]]);
    };
    auto stageB = [&](int tau) {
        const int b = tau & 1, ko = tau * 64;
#pragma unroll
        for (int h = 0; h < 2; ++h)
#pragma unroll
            for (int j = 0; j < 2; ++j)
                gld16(Bt + bSrc[h][j] + ko, &Bs[b][dstE[h][j]]);
    };
    auto readA = [&](int set, int b, int grp, int kh) {
        const char* ab = reinterpret_cast<const char*>(&As[b][0]);
#pragma unroll
        for (int q = 0; q < 4; ++q)
            afr[set][q] = *reinterpret_cast<const bf16x8*>(ab + aoff[grp][kh][q]);
    };
    auto readB = [&](int b, int kh) {
        const char* bb = reinterpret_cast<const char*>(&Bs[b][0]);
#pragma unroll
        for (int n = 0; n < 4; ++n)
            bfr[kh][n] = *reinterpret_cast<const bf16x8*>(bb + boff[kh][n]);
    };

    stageB(0); stageA(0); stageB(1); stageA(1);
    asm volatile("s_waitcnt vmcnt(8)" ::: "memory");
    __builtin_amdgcn_s_barrier();
    readA(0, 0, 0, 0);
    readB(0, 0);
    asm volatile("s_waitcnt lgkmcnt(0)" ::: "memory");
    __builtin_amdgcn_sched_barrier(0);

#pragma unroll
    for (int tau = 0; tau < NKT; ++tau) {
#pragma unroll
        for (int p = 0; p < 4; ++p) {
            const int pi  = tau * 4 + p;
            const int grp = p & 1, kh = p >> 1;

            if (p == 2 && tau + 2 < NKT) stageB(tau + 2);
            if (p == 3 && tau + 2 < NKT) stageA(tau + 2);

            if (pi + 1 < NKT * 4) {
                const int pn   = (p + 1) & 3;
                const int taun = tau + (p == 3);
                const int bn   = taun & 1;
                readA((pi + 1) & 1, bn, pn & 1, pn >> 1);
                if (pn == 0 || pn == 2) readB(bn, pn >> 1);
            }

            __builtin_amdgcn_s_setprio(1);
#pragma unroll
            for (int q = 0; q < 4; ++q)
#pragma unroll
                for (int n = 0; n < 4; ++n)
                    acc[grp * 4 + q][n] = __builtin_amdgcn_mfma_f32_16x16x32_bf16(
                        afr[pi & 1][q], bfr[kh][n], acc[grp * 4 + q][n], 0, 0, 0);
            __builtin_amdgcn_s_setprio(0);

            asm volatile("s_waitcnt lgkmcnt(0)" ::: "memory");
            __builtin_amdgcn_sched_barrier(0);
            if (p == 2) {
                if (tau + 2 < NKT)
                    asm volatile("s_waitcnt vmcnt(4)" ::: "memory");
                else
                    asm volatile("s_waitcnt vmcnt(0)" ::: "memory");
            }
            __builtin_amdgcn_s_barrier();
        }
    }

    const int ldo = NT * 256;
#pragma unroll
    for (int n = 0; n < 4; ++n) {
        int col = n0 + wc * 64 + n * 16 + r16;
        float b = bias[col];
#pragma unroll
        for (int i = 0; i < 8; ++i)
#pragma unroll
            for (int j = 0; j < 4; ++j) {
                int row = m0 + wr * 128 + i * 16 + g * 4 + j;
                outp[(size_t)row * ldo + col] = cvt(acc[i][n][j] + b);
            }
    }
}

// ---------------------------------------------------------------------------
// FUSED attention + projection v2 — overlapped loads, conflict-fixed.
// One block per window (512 thr, 8 waves). Per head h:
//   top:   issue gld16 Q/K[h+1] (rotate-slot swizzled [128][64], dbuf)
//          issue V[h+1] uint4 loads (reg-staged, T14)
//   QK^T (wave = 16 Q-rows) -> softmax -> P -> PV (reads Vt[h&1])
//   packWrite Vt[(h+1)&1]  (rotated stores: 2-way banks; implicit vmcnt
//                           wait on V regs also drains the Q/K gld16s)
//   Oh write -> __syncthreads (A) -> proj (Wp frags DIRECT from global,
//   L2-hot, waves own disjoint c-ranges) -> __syncthreads (B)
// pacc[c][q] (out^T) accumulates across heads; float4 epilogue via ord_s.
// LDS: Qb 32K + Kb 32K + Vt 34K + P 34K + Oh 18K = 150KB, 1 block/CU.
// ---------------------------------------------------------------------------
__global__ __launch_bounds__(512) void k_attn_proj(
    const bf16* __restrict__ qkv_s, const bf16* __restrict__ Wp_t,
    const float* __restrict__ bproj, const int* __restrict__ order,
    float* __restrict__ out)
{
    __shared__ __align__(16) char smem[153600];
    __shared__ int ord_s[KWIN];
    bf16* Qb = reinterpret_cast<bf16*>(smem);                    // [2][8192]
    bf16* Kb = reinterpret_cast<bf16*>(smem + 32768);            // [2][8192]
    unsigned short* Vtu = reinterpret_cast<unsigned short*>(smem + 65536); // [2][64*136]
    const bf16* Vtb = reinterpret_cast<const bf16*>(smem + 65536);
    bf16 (*P)[136] = reinterpret_cast<bf16 (*)[136]>(smem + 100352);
    bf16 (*Oh)[72] = reinterpret_cast<bf16 (*)[72]>(smem + 135168);

    const int t    = threadIdx.x;
    const int lane = t & 63;
    const int wv   = t >> 6;          // 0..7
    const int g    = lane >> 4, r16 = lane & 15;
    const int w    = blockIdx.x;

    if (t < KWIN) ord_s[t] = order[w * KWIN + t];

    const bf16* base = qkv_s + (size_t)w * KWIN * C3;

    // ---- Q/K staging maps: chunks L = t and t+512 of a 128x64 tile ----
    // row = L>>3, phys slot p = L&7, source slot s = (p-row)&7.
    int qsrc[2], qdst[2];
#pragma unroll
    for (int j = 0; j < 2; ++j) {
        int L = t + j * 512;
        int row = L >> 3, p = L & 7, s = (p - row) & 7;
        qsrc[j] = row * C3 + s * 8;
        qdst[j] = j * 4096 + wv * 512;      // wave-uniform elem base
    }
    auto stageQK = [&](int hh) {
        const int b = hh & 1;
#pragma unroll
        for (int j = 0; j < 2; ++j) {
            gld16(base + hh * HD + qsrc[j],        Qb + b * 8192 + qdst[j]);
            gld16(base + CDIM + hh * HD + qsrc[j], Kb + b * 8192 + qdst[j]);
        }
    };

    // ---- V: reg-stage + rotated transpose-write ----
    const int vtok = t >> 3;            // 0..63 (chunk t); chunk t+512 -> +64
    const int vd0  = (t & 7) * 8;
    const int vr   = t & 7;
    int vaddr[8];
#pragma unroll
    for (int k = 0; k < 8; ++k)
        vaddr[k] = (vd0 + ((k + vr) & 7)) * 136 + vtok;

    auto loadV = [&](int hh, uint4& ua, uint4& ub) {
        const float* dummy = nullptr; (void)dummy;
        ua = *reinterpret_cast<const uint4*>(
            base + (size_t)vtok * C3 + 2 * CDIM + hh * HD + vd0);
        ub = *reinterpret_cast<const uint4*>(
            base + (size_t)(vtok + 64) * C3 + 2 * CDIM + hh * HD + vd0);
    };
    auto packV = [&](int hh, uint4 ua, uint4 ub) {
        const int b = hh & 1;
        uint4 ra = rot128(ua, vr), rb = rot128(ub, vr);
        uint32_t wa[4] = {ra.x, ra.y, ra.z, ra.w};
        uint32_t wb[4] = {rb.x, rb.y, rb.z, rb.w};
        unsigned short* vt = Vtu + b * 8704;
#pragma unroll
        for (int k = 0; k < 8; ++k) {
            vt[vaddr[k]]      = (unsigned short)(wa[k >> 1] >> ((k & 1) * 16));
            vt[vaddr[k] + 64] = (unsigned short)(wb[k >> 1] >> ((k & 1) * 16));
        }
    };

    f32x4 pacc[4][8];
    const f32x4 z = {0.f, 0.f, 0.f, 0.f};
#pragma unroll
    for (int ci = 0; ci < 4; ++ci)
#pragma unroll
        for (int qi = 0; qi < 8; ++qi) pacc[ci][qi] = z;

    const float scale = 0.125f;   // hd^-0.5

    // ---------------- prologue: head 0's Q/K + V ----------------
    {
        stageQK(0);
        uint4 ua, ub;
        loadV(0, ua, ub);
        packV(0, ua, ub);        // implicit vmcnt wait drains the gld16s too
        __syncthreads();
    }

    for (int h = 0; h < NH; ++h) {
        const int qb = h & 1;
        uint4 vA, vB;
        if (h < NH - 1) {
            stageQK(h + 1);
            loadV(h + 1, vA, vB);
        }

        // ---- QK^T: wave owns rows [wv*16, wv*16+16) ----
        f32x4 sc[8];
#pragma unroll
        for (int n = 0; n < 8; ++n) sc[n] = z;
#pragma unroll
        for (int ks = 0; ks < 2; ++ks) {
            int qrow = wv * 16 + r16;
            bf16x8 aq = *reinterpret_cast<const bf16x8*>(
                Qb + qb * 8192 + qrow * 64 + (((ks * 4 + g) + qrow) & 7) * 8);
#pragma unroll
            for (int n = 0; n < 8; ++n) {
                int krow = n * 16 + r16;
                bf16x8 bk = *reinterpret_cast<const bf16x8*>(
                    Kb + qb * 8192 + krow * 64 + (((ks * 4 + g) + krow) & 7) * 8);
                sc[n] = __builtin_amdgcn_mfma_f32_16x16x32_bf16(
                    aq, bk, sc[n], 0, 0, 0);
            }
        }

        // ---- softmax (rows wv*16 + g*4 + j) ----
        float inv_sum[4];
#pragma unroll
        for (int j = 0; j < 4; ++j) {
            float mx = -3.0e38f;
#pragma unroll
            for (int n = 0; n < 8; ++n) mx = fmaxf(mx, sc[n][j]);
            mx = fmaxf(mx, __shfl_xor(mx, 1));
            mx = fmaxf(mx, __shfl_xor(mx, 2));
            mx = fmaxf(mx, __shfl_xor(mx, 4));
            mx = fmaxf(mx, __shfl_xor(mx, 8));
            mx *= scale;
            float ssum = 0.f;
#pragma unroll
            for (int n = 0; n < 8; ++n) {
                float p = __expf(sc[n][j] * scale - mx);
                sc[n][j] = p;
                ssum += p;
            }
            ssum += __shfl_xor(ssum, 1);
            ssum += __shfl_xor(ssum, 2);
            ssum += __shfl_xor(ssum, 4);
            ssum += __shfl_xor(ssum, 8);
            inv_sum[j] = 1.f / ssum;
        }

        // ---- P (bf16), wave-private rows ----
#pragma unroll
        for (int n = 0; n < 8; ++n)
#pragma unroll
            for (int j = 0; j < 4; ++j)
                P[wv * 16 + g * 4 + j][n * 16 + r16] =
                    cvt(sc[n][j] * inv_sum[j]);

        // ---- Wp frags for this head (global, L2-hot; cover = PV phase) ----
        bf16x8 af[2][4];
#pragma unroll
        for (int ks = 0; ks < 2; ++ks)
#pragma unroll
            for (int ci = 0; ci < 4; ++ci)
                af[ks][ci] = *reinterpret_cast<const bf16x8*>(
                    Wp_t + (size_t)(wv * 64 + ci * 16 + r16) * CDIM
                         + h * HD + ks * 32 + g * 8);

        // ---- O = P V  (16x64 per wave) ----
        f32x4 o[4];
#pragma unroll
        for (int n = 0; n < 4; ++n) o[n] = z;
#pragma unroll
        for (int kt = 0; kt < 4; ++kt) {
            bf16x8 ap = *reinterpret_cast<const bf16x8*>(
                &P[wv * 16 + r16][kt * 32 + g * 8]);
#pragma unroll
            for (int n = 0; n < 4; ++n) {
                bf16x8 bvv = *reinterpret_cast<const bf16x8*>(
                    Vtb + qb * 8704 + (n * 16 + r16) * 136 + kt * 32 + g * 8);
                o[n] = __builtin_amdgcn_mfma_f32_16x16x32_bf16(
                    ap, bvv, o[n], 0, 0, 0);
            }
        }

        // ---- write Vt for next head (waits V regs -> drains gld16s) ----
        if (h < NH - 1) packV(h + 1, vA, vB);

        // ---- Oh ----
#pragma unroll
        for (int n = 0; n < 4; ++n)
#pragma unroll
            for (int j = 0; j < 4; ++j)
                Oh[wv * 16 + g * 4 + j][n * 16 + r16] = cvt(o[n][j]);

        __syncthreads();   // A: Oh visible; Q/K[h+1], Vt[h+1] landed

        // ---- proj partial: pacc[c][q] += Wp[c][d] * Oh[q][d] ----
#pragma unroll
        for (int ks = 0; ks < 2; ++ks) {
            __builtin_amdgcn_s_setprio(1);
#pragma unroll
            for (int qi = 0; qi < 8; ++qi) {
                bf16x8 bq = *reinterpret_cast<const bf16x8*>(
                    &Oh[qi * 16 + r16][ks * 32 + g * 8]);
#pragma unroll
                for (int ci = 0; ci < 4; ++ci)
                    pacc[ci][qi] = __builtin_amdgcn_mfma_f32_16x16x32_bf16(
                        af[ks][ci], bq, pacc[ci][qi], 0, 0, 0);
            }
            __builtin_amdgcn_s_setprio(0);
        }
        __syncthreads();   // B: proj done -> Oh/P/buffers reusable
    }

    // ---- epilogue: D[c][q] = out^T; float4 stores via ord_s ----
#pragma unroll
    for (int ci = 0; ci < 4; ++ci) {
        int c0 = wv * 64 + ci * 16 + g * 4;
        float4 bp = *reinterpret_cast<const float4*>(bproj + c0);
#pragma unroll
        for (int qi = 0; qi < 8; ++qi) {
            int q = qi * 16 + r16;
            float4 v;
            v.x = pacc[ci][qi][0] + bp.x;
            v.y = pacc[ci][qi][1] + bp.y;
            v.z = pacc[ci][qi][2] + bp.z;
            v.w = pacc[ci][qi][3] + bp.w;
            *reinterpret_cast<float4*>(
                out + (size_t)ord_s[q] * CDIM + c0) = v;
        }
    }
}

// ---------------------------------------------------------------------------
extern "C" void kernel_launch(void* const* d_in, const int* in_sizes, int n_in,
                              void* d_out, int out_size, void* d_ws, size_t ws_size,
                              hipStream_t stream)
{
    const float* feat    = (const float*)d_in[0];
    const float* Wqkv    = (const float*)d_in[1];
    const float* bqkv    = (const float*)d_in[2];
    const float* Wproj   = (const float*)d_in[3];
    const float* bproj   = (const float*)d_in[4];
    const int*   order   = (const int*)d_in[5];
    float* out = (float*)d_out;

    const size_t qkv_bytes = (size_t)N_PTS * C3 * sizeof(bf16);    // 402.7 MB
    const size_t gat_bytes = (size_t)N_PTS * CDIM * sizeof(bf16);  // 134.2 MB
    const size_t wq_bytes  = (size_t)C3 * CDIM * sizeof(bf16);
    const size_t wp_bytes  = (size_t)CDIM * CDIM * sizeof(bf16);
    if (ws_size < qkv_bytes + gat_bytes + wq_bytes + wp_bytes) return;

    bf16* qkv_s   = (bf16*)d_ws;
    bf16* feat_g  = (bf16*)((char*)d_ws + qkv_bytes);
    bf16* Wqkv_t  = (bf16*)((char*)d_ws + qkv_bytes + gat_bytes);
    bf16* Wproj_t = (bf16*)((char*)d_ws + qkv_bytes + gat_bytes + wq_bytes);

    k_prep<<<dim3((CDIM * C3 + CDIM * CDIM + 255) / 256), 256, 0, stream>>>(
        Wqkv, Wproj, Wqkv_t, Wproj_t);
    k_gather<<<dim3(N_PTS / 2), 256, 0, stream>>>(feat, order, feat_g);
    // qkv GEMM: [131072 x 1536] = feat_g @ Wqkv_t^T  (512 x 6 = 3072 blocks)
    k_gemm8<C3 / 256><<<dim3((N_PTS / 256) * (C3 / 256)), 512, 0, stream>>>(
        feat_g, Wqkv_t, bqkv, qkv_s);
    // fused attention + projection v2: one block per window
    k_attn_proj<<<dim3(N_PTS / KWIN), 512, 0, stream>>>(
        qkv_s, Wproj_t, bproj, order, out);
}

// Round 14
// 601.130 us; speedup vs baseline: 1.1026x; 1.0878x over previous
//
#include <hip/hip_runtime.h>
#include <hip/hip_bf16.h>
#include <cstdint>
#include <cstddef>

typedef __bf16 bf16;
typedef __bf16 bf16x8 __attribute__((ext_vector_type(8)));
typedef float f32x4 __attribute__((ext_vector_type(4)));

#define N_PTS 131072
#define CDIM  512
#define C3    1536
#define HD    64
#define NH    8
#define KWIN  128

static __device__ __forceinline__ bf16 cvt(float x) { return (bf16)x; }

// async global->LDS, 16B per lane. LDS dest = wave-uniform base + lane*16.
static __device__ __forceinline__ void gld16(const bf16* g, bf16* l) {
    __builtin_amdgcn_global_load_lds(
        (const __attribute__((address_space(1))) void*)g,
        (__attribute__((address_space(3))) void*)l, 16, 0, 0);
}

// ---------------------------------------------------------------------------
// Weight prep: transpose + cast f32 -> bf16.  Wt[col][k] = W[k][col].
// ---------------------------------------------------------------------------
__global__ __launch_bounds__(256) void k_prep(
    const float* __restrict__ Wqkv, const float* __restrict__ Wproj,
    bf16* __restrict__ Wqkv_t, bf16* __restrict__ Wproj_t)
{
    int idx = blockIdx.x * 256 + threadIdx.x;
    if (idx < CDIM * C3) {
        int k = idx / C3, c = idx % C3;
        Wqkv_t[(size_t)c * CDIM + k] = cvt(Wqkv[idx]);
    } else {
        int j = idx - CDIM * C3;
        if (j < CDIM * CDIM) {
            int k = j / CDIM, c = j % CDIM;
            Wproj_t[(size_t)c * CDIM + k] = cvt(Wproj[j]);
        }
    }
}

// ---------------------------------------------------------------------------
// GEMM (R8 structure = best total so far), + DEPTH-2 fused-gather pipeline:
//   out[m,n] = A[m,:] @ Bt[n,:]^T + bias[n]
// 128x256 tile, BK=32, 8 waves (2M x 4N), wave owns 64x64 (acc 64 AGPR ->
// ~72 regs total -> 2 blocks/CU). 2-deep LDS ring: (A 8KB + B 16KB) x 2.
//
// B (both paths): gld16 into LDS, pre-swizzled global source (rotate-permute:
//   16B slot p of row holds k-slot (p-(row>>1))&3; reader byte =
//   row*64 + (((g+(row>>1))&3)<<4)) — verified conflict-free R4-R13.
// A:
//  GATHER=false (proj): gld16, same as B.
//  GATHER=true (qkv): reg-staged fused gather, DEPTH-2 in flight:
//   step-s TOP  issues f32(s+3) into set (s+1)&1  (2x float4 per thread);
//   step-s END  packs s+2 from set s&1 (cvt->bf16x8, one ds_write_b128) —
//   the consumed loads were issued 1.5-2 compute phases ago (~1100 cyc),
//   covering the ~900 cyc HBM latency (R8's 1-deep version exposed ~400cyc).
//   B-residency is now an explicit counted wait: after pack+stageB(s+2),
//   outstanding = B(s+1):2 (oldest), f32(s+3):2, B(s+2):2 -> vmcnt(4)
//   retires exactly B(s+1). s=13: vmcnt(2). s=14: vmcnt(0). Never stalls
//   the pipe on newer loads.
// ---------------------------------------------------------------------------
template <bool GATHER, bool F32OUT, int NT>
__global__ __launch_bounds__(512, 4) void k_gemm(
    const void* __restrict__ Ag_, const bf16* __restrict__ Bt,
    const float* __restrict__ bias, const int* __restrict__ order,
    void* __restrict__ outp)
{
    __shared__ __align__(16) bf16 As[2][128 * 32];   // 16 KB
    __shared__ __align__(16) bf16 Bs[2][256 * 32];   // 32 KB
    __shared__ int ord_s[128];

    const int t    = threadIdx.x;
    const int lane = t & 63;
    const int wv   = t >> 6;          // 0..7
    const int wr   = wv >> 2;         // 0..1  (M half: 64 rows)
    const int wc   = wv & 3;          // 0..3  (N quarter: 64 cols)
    const int g    = lane >> 4, r16 = lane & 15;

    const int nwg = gridDim.x;
    const int bid = blockIdx.x;
    const int swz = (bid & 7) * (nwg >> 3) + (bid >> 3);  // grids are %8==0
    const int m0  = (swz / NT) * 128;
    const int n0  = (swz % NT) * 256;

    const float* Af = (const float*)Ag_;
    const bf16*  Ab = (const bf16*)Ag_;
    const int NKT = CDIM / 32;   // 16

    if (GATHER) {
        if (t < 128) ord_s[t] = order[m0 + t];
        __syncthreads();
    }

    // ---- A chunk ownership (chunk t of 512): row, phys slot, src k-slot ----
    const int rowA = t >> 2;
    const int ksA  = ((t & 3) - (rowA >> 1)) & 3;
    const float* gsrcA = GATHER
        ? Af + (size_t)ord_s[rowA] * CDIM + ksA * 8 : nullptr;
    const bf16* srcA_l = Ab + (size_t)(m0 + rowA) * CDIM + ksA * 8;

    // ---- B staging: chunks t and t+512 (rows 0..127 / 128..255) ----
    const int rB0 = t >> 2,        sB0 = ((t & 3) - (rB0 >> 1)) & 3;
    const int rB1 = rB0 + 128,     sB1 = ((t & 3) - (rB1 >> 1)) & 3;
    const bf16* srcB0 = Bt + (size_t)(n0 + rB0) * CDIM + sB0 * 8;
    const bf16* srcB1 = Bt + (size_t)(n0 + rB1) * CDIM + sB1 * 8;

    // ---- fragment read byte-offsets (rotate-permuted slots) ----
    int aoff[4], boff[4];
#pragma unroll
    for (int m = 0; m < 4; ++m) {
        int row = wr * 64 + m * 16 + r16;
        aoff[m] = row * 64 + (((g + (row >> 1)) & 3) << 4);
    }
#pragma unroll
    for (int n = 0; n < 4; ++n) {
        int row = wc * 64 + n * 16 + r16;
        boff[n] = row * 64 + (((g + (row >> 1)) & 3) << 4);
    }

    f32x4 acc[4][4];
    const f32x4 z = {0.f, 0.f, 0.f, 0.f};
#pragma unroll
    for (int m = 0; m < 4; ++m)
#pragma unroll
        for (int n = 0; n < 4; ++n) acc[m][n] = z;

    auto stageB = [&](int s) {
        const int b = s & 1;
        gld16(srcB0 + s * 32, &Bs[b][(size_t)wv * 64 * 8]);
        gld16(srcB1 + s * 32, &Bs[b][(size_t)(512 + wv * 64) * 8]);
    };
    auto stageA_l = [&](int s) {
        const int b = s & 1;
        gld16(srcA_l + s * 32, &As[b][(size_t)wv * 64 * 8]);
    };
    auto packA = [&](int s, float4 fa, float4 fb) {
        union { bf16 e[8]; uint4 u; } pk;
        pk.e[0] = cvt(fa.x); pk.e[1] = cvt(fa.y);
        pk.e[2] = cvt(fa.z); pk.e[3] = cvt(fa.w);
        pk.e[4] = cvt(fb.x); pk.e[5] = cvt(fb.y);
        pk.e[6] = cvt(fb.z); pk.e[7] = cvt(fb.w);
        *reinterpret_cast<uint4*>(
            reinterpret_cast<char*>(&As[s & 1][0]) + t * 16) = pk.u;
    };
    auto compute = [&](int s) {
        const int b = s & 1;
        const char* ab = reinterpret_cast<const char*>(&As[b][0]);
        const char* bb = reinterpret_cast<const char*>(&Bs[b][0]);
        bf16x8 af[4], bvv[4];
#pragma unroll
        for (int m = 0; m < 4; ++m)
            af[m] = *reinterpret_cast<const bf16x8*>(ab + aoff[m]);
#pragma unroll
        for (int n = 0; n < 4; ++n)
            bvv[n] = *reinterpret_cast<const bf16x8*>(bb + boff[n]);
        __builtin_amdgcn_s_setprio(1);
#pragma unroll
        for (int m = 0; m < 4; ++m)
#pragma unroll
            for (int n = 0; n < 4; ++n)
                acc[m][n] = __builtin_amdgcn_mfma_f32_16x16x32_bf16(
                    af[m], bvv[n], acc[m][n], 0, 0, 0);
        __builtin_amdgcn_s_setprio(0);
    };

    float4 fp[2][2];   // depth-2 gather pipeline regs (parity-indexed, static)

    // ---------------- prologue ----------------
    if (GATHER) {
        float4 fa0 = *reinterpret_cast<const float4*>(gsrcA);
        float4 fb0 = *reinterpret_cast<const float4*>(gsrcA + 4);
        float4 fa1 = *reinterpret_cast<const float4*>(gsrcA + 32);
        float4 fb1 = *reinterpret_cast<const float4*>(gsrcA + 36);
        stageB(0); stageB(1);
        packA(0, fa0, fb0);
        packA(1, fa1, fb1);
        // pipeline set 0 <- f32(step 2)
        fp[0][0] = *reinterpret_cast<const float4*>(gsrcA + 64);
        fp[0][1] = *reinterpret_cast<const float4*>(gsrcA + 68);
        // outstanding: B(0):2 oldest, B(1):2, f32(2):2 -> retire B(0)
        asm volatile("s_waitcnt vmcnt(4) lgkmcnt(0)" ::: "memory");
        __builtin_amdgcn_s_barrier();
    } else {
        stageA_l(0); stageB(0);
        stageA_l(1); stageB(1);
        // outstanding: tile0(3) oldest, tile1(3) -> retire tile0
        asm volatile("s_waitcnt vmcnt(3)" ::: "memory");
        __builtin_amdgcn_s_barrier();
    }

    // ---------------- main loop ----------------
#pragma unroll
    for (int s = 0; s < NKT; ++s) {
        // top: issue f32 for step s+3 into set (s+1)&1
        if (GATHER && s + 3 < NKT) {
            fp[(s + 1) & 1][0] = *reinterpret_cast<const float4*>(
                gsrcA + (size_t)(s + 3) * 32);
            fp[(s + 1) & 1][1] = *reinterpret_cast<const float4*>(
                gsrcA + (size_t)(s + 3) * 32 + 4);
        }
        compute(s);
        if (s == NKT - 1) break;
        asm volatile("s_waitcnt lgkmcnt(0)" ::: "memory");
        __builtin_amdgcn_s_barrier();           // all waves done reading buf[s&1]
        if (GATHER) {
            if (s + 2 < NKT) {
                packA(s + 2, fp[s & 1][0], fp[s & 1][1]);  // waits set s&1 only
                stageB(s + 2);
                asm volatile("s_waitcnt lgkmcnt(0)" ::: "memory");
                if (s + 3 < NKT) {
                    // outstanding: B(s+1):2 oldest, f32(s+3):2, B(s+2):2
                    asm volatile("s_waitcnt vmcnt(4)" ::: "memory");
                } else {
                    // s == NKT-3: outstanding B(s+1):2 oldest, B(s+2):2
                    asm volatile("s_waitcnt vmcnt(2)" ::: "memory");
                }
            } else {  // s == NKT-2: B(NKT-1) still outstanding
                asm volatile("s_waitcnt vmcnt(0)" ::: "memory");
            }
        } else {
            if (s + 2 < NKT) {
                stageA_l(s + 2); stageB(s + 2);
                // outstanding: tile s+1 (3) oldest, tile s+2 (3)
                asm volatile("s_waitcnt vmcnt(3)" ::: "memory");
            } else {
                asm volatile("s_waitcnt vmcnt(0)" ::: "memory");
            }
        }
        __builtin_amdgcn_s_barrier();
    }

    // ---------------- epilogue: D layout col=lane&15, row=(lane>>4)*4+j ----
    const int ldo = NT * 256;
#pragma unroll
    for (int n = 0; n < 4; ++n) {
        int col = n0 + wc * 64 + n * 16 + r16;
        float b = bias[col];
#pragma unroll
        for (int m = 0; m < 4; ++m)
#pragma unroll
            for (int j = 0; j < 4; ++j) {
                int row = m0 + wr * 64 + m * 16 + g * 4 + j;
                if (F32OUT)
                    reinterpret_cast<float*>(outp)[(size_t)row * ldo + col] =
                        acc[m][n][j] + b;
                else
                    reinterpret_cast<bf16*>(outp)[(size_t)row * ldo + col] =
                        cvt(acc[m][n][j] + b);
            }
    }
}

// ---------------------------------------------------------------------------
// Attention: one block per (window, head). 4 waves, each owns 32 query rows.
// Output rows are SCATTERED to attn_g[order[w*128+tok]] so that k_proj's A
// operand is sequential (order[inverse[n]] == n).
// ---------------------------------------------------------------------------
__global__ __launch_bounds__(256) void k_attn(
    const bf16* __restrict__ qkv_s, const int* __restrict__ order,
    bf16* __restrict__ attn_g)
{
    __shared__ __align__(16) char smem[36864 + 64 * 136 * 2];
    __shared__ int ord_s[KWIN];
    bf16 (*Q)[72]   = reinterpret_cast<bf16 (*)[72]>(smem);
    bf16 (*Kt)[72]  = reinterpret_cast<bf16 (*)[72]>(smem + 128 * 72 * 2);
    bf16 (*P)[136]  = reinterpret_cast<bf16 (*)[136]>(smem);          // overlaps Q,Kt
    bf16 (*Vt)[136] = reinterpret_cast<bf16 (*)[136]>(smem + 36864);  // V transposed

    const int t    = threadIdx.x;
    const int lane = t & 63;
    const int wv   = t >> 6;
    const int g    = lane >> 4, r16 = lane & 15;
    const int h    = blockIdx.x;
    const int w    = blockIdx.y;

    const bf16* base = qkv_s + (size_t)w * KWIN * C3 + h * HD;

    if (t < KWIN) ord_s[t] = order[w * KWIN + t];

    // stage Q, K (row-major [tok][d]) and V transposed [d][tok]
#pragma unroll
    for (int it = 0; it < 4; ++it) {
        int s   = it * 256 + t;      // 0..1023
        int tok = s >> 3;
        int c8  = (s & 7) << 3;
        size_t roff = (size_t)tok * C3 + c8;
        *reinterpret_cast<uint4*>(&Q[tok][c8])  =
            *reinterpret_cast<const uint4*>(base + roff);
        *reinterpret_cast<uint4*>(&Kt[tok][c8]) =
            *reinterpret_cast<const uint4*>(base + roff + CDIM);
        uint4 vvec = *reinterpret_cast<const uint4*>(base + roff + 2 * CDIM);
        const bf16* ve = reinterpret_cast<const bf16*>(&vvec);
#pragma unroll
        for (int i = 0; i < 8; ++i) Vt[c8 + i][tok] = ve[i];
    }
    __syncthreads();

    // S = Q K^T for rows [wv*32, wv*32+32)
    f32x4 sc[2][8];
    const f32x4 z = {0.f, 0.f, 0.f, 0.f};
#pragma unroll
    for (int m = 0; m < 2; ++m)
#pragma unroll
        for (int n = 0; n < 8; ++n) sc[m][n] = z;

#pragma unroll
    for (int ks = 0; ks < 2; ++ks) {
        bf16x8 aq[2];
#pragma unroll
        for (int m = 0; m < 2; ++m)
            aq[m] = *reinterpret_cast<const bf16x8*>(
                &Q[wv * 32 + m * 16 + r16][ks * 32 + g * 8]);
#pragma unroll
        for (int n = 0; n < 8; ++n) {
            bf16x8 bk = *reinterpret_cast<const bf16x8*>(
                &Kt[n * 16 + r16][ks * 32 + g * 8]);
#pragma unroll
            for (int m = 0; m < 2; ++m)
                sc[m][n] = __builtin_amdgcn_mfma_f32_16x16x32_bf16(
                    aq[m], bk, sc[m][n], 0, 0, 0);
        }
    }

    // softmax (f32), row-parallel over 16-lane groups
    const float scale = 0.125f;   // hd^-0.5
    float inv_sum[2][4];
#pragma unroll
    for (int m = 0; m < 2; ++m) {
#pragma unroll
        for (int j = 0; j < 4; ++j) {
            float mx = -3.0e38f;
#pragma unroll
            for (int n = 0; n < 8; ++n) mx = fmaxf(mx, sc[m][n][j]);
            mx = fmaxf(mx, __shfl_xor(mx, 1));
            mx = fmaxf(mx, __shfl_xor(mx, 2));
            mx = fmaxf(mx, __shfl_xor(mx, 4));
            mx = fmaxf(mx, __shfl_xor(mx, 8));
            mx *= scale;
            float ssum = 0.f;
#pragma unroll
            for (int n = 0; n < 8; ++n) {
                float p = __expf(sc[m][n][j] * scale - mx);
                sc[m][n][j] = p;
                ssum += p;
            }
            ssum += __shfl_xor(ssum, 1);
            ssum += __shfl_xor(ssum, 2);
            ssum += __shfl_xor(ssum, 4);
            ssum += __shfl_xor(ssum, 8);
            inv_sum[m][j] = 1.f / ssum;
        }
    }

    __syncthreads();   // all waves done reading Q/Kt before P overwrites them

    // write normalized P (bf16)
#pragma unroll
    for (int m = 0; m < 2; ++m)
#pragma unroll
        for (int n = 0; n < 8; ++n)
#pragma unroll
            for (int j = 0; j < 4; ++j)
                P[wv * 32 + m * 16 + g * 4 + j][n * 16 + r16] =
                    cvt(sc[m][n][j] * inv_sum[m][j]);

    // O = P V   (32x64 per wave)
    f32x4 o[2][4];
#pragma unroll
    for (int m = 0; m < 2; ++m)
#pragma unroll
        for (int n = 0; n < 4; ++n) o[m][n] = z;

#pragma unroll
    for (int kt = 0; kt < 4; ++kt) {
        bf16x8 ap[2];
#pragma unroll
        for (int m = 0; m < 2; ++m)
            ap[m] = *reinterpret_cast<const bf16x8*>(
                &P[wv * 32 + m * 16 + r16][kt * 32 + g * 8]);
#pragma unroll
        for (int n = 0; n < 4; ++n) {
            bf16x8 bvv = *reinterpret_cast<const bf16x8*>(
                &Vt[n * 16 + r16][kt * 32 + g * 8]);
#pragma unroll
            for (int m = 0; m < 2; ++m)
                o[m][n] = __builtin_amdgcn_mfma_f32_16x16x32_bf16(
                    ap[m], bvv, o[m][n], 0, 0, 0);
        }
    }

    // scatter rows to unserialized position: attn_g[order[i]] = ser[i]
#pragma unroll
    for (int m = 0; m < 2; ++m)
#pragma unroll
        for (int n = 0; n < 4; ++n)
#pragma unroll
            for (int j = 0; j < 4; ++j) {
                int tok  = wv * 32 + m * 16 + g * 4 + j;
                int d    = n * 16 + r16;
                int drow = ord_s[tok];
                attn_g[(size_t)drow * CDIM + h * HD + d] = cvt(o[m][n][j]);
            }
}

// ---------------------------------------------------------------------------
extern "C" void kernel_launch(void* const* d_in, const int* in_sizes, int n_in,
                              void* d_out, int out_size, void* d_ws, size_t ws_size,
                              hipStream_t stream)
{
    const float* feat    = (const float*)d_in[0];
    const float* Wqkv    = (const float*)d_in[1];
    const float* bqkv    = (const float*)d_in[2];
    const float* Wproj   = (const float*)d_in[3];
    const float* bproj   = (const float*)d_in[4];
    const int*   order   = (const int*)d_in[5];
    float* out = (float*)d_out;

    const size_t qkv_bytes  = (size_t)N_PTS * C3 * sizeof(bf16);    // 402.7 MB
    const size_t gat_bytes  = (size_t)N_PTS * CDIM * sizeof(bf16);  // 134.2 MB (attn_g)
    const size_t wq_bytes   = (size_t)C3 * CDIM * sizeof(bf16);
    const size_t wp_bytes   = (size_t)CDIM * CDIM * sizeof(bf16);
    if (ws_size < qkv_bytes + gat_bytes + wq_bytes + wp_bytes) return;

    bf16* qkv_s   = (bf16*)d_ws;
    bf16* attn_g  = (bf16*)((char*)d_ws + qkv_bytes);
    bf16* Wqkv_t  = (bf16*)((char*)d_ws + qkv_bytes + gat_bytes);
    bf16* Wproj_t = (bf16*)((char*)d_ws + qkv_bytes + gat_bytes + wq_bytes);

    k_prep<<<dim3((CDIM * C3 + CDIM * CDIM + 255) / 256), 256, 0, stream>>>(
        Wqkv, Wproj, Wqkv_t, Wproj_t);
    // qkv GEMM with fused gather: [131072 x 1536] = bf16(feat[order]) @ Wqkv_t^T
    k_gemm<true, false, C3 / 256>
        <<<dim3((N_PTS / 128) * (C3 / 256)), 512, 0, stream>>>(
        feat, Wqkv_t, bqkv, order, qkv_s);
    // attention (reads qkv_s, scatters into attn_g)
    k_attn<<<dim3(NH, N_PTS / KWIN), 256, 0, stream>>>(qkv_s, order, attn_g);
    // proj GEMM: [131072 x 512] = attn_g @ Wproj_t^T  (f32 out)
    k_gemm<false, true, CDIM / 256>
        <<<dim3((N_PTS / 128) * (CDIM / 256)), 512, 0, stream>>>(
        attn_g, Wproj_t, bproj, order, out);
}